// Round 12
// baseline (229.196 us; speedup 1.0000x reference)
//
#include <hip/hip_runtime.h>
#include <hip/hip_bf16.h>
#include <hip/hip_cooperative_groups.h>

namespace cg = cooperative_groups;

// Problem constants
#define DM   1024
#define NH   16
#define DK   64
#define RK   16
#define BB   2
#define LL   2048
#define TT   (BB*LL)
#define NSPL 2             // split-K factor

// r21: r20 with the outred invS indexing bug FIXED. r20's stage_outred
// computed base = (b*LL + t0 + r)*NSPL*NH, but t0 is the GLOBAL row (b is
// already baked in) -> double-counted b*LL for b=1, read 512KB past denP,
// garbage inv -> absmax 6.9e31. Fix: base = (t0+r)*NSPL*NH, matching the
// attn-side write ((b*LL+l)*NSPL+ksp)*NH+h. Everything else identical:
// single cooperative dispatch (grid 1024x256, grid.sync between stages),
// exp2 fold (QSCALE=0.25*log2e), transposed denP, classic 4-launch fallback.

typedef float f4   __attribute__((ext_vector_type(4)));
typedef float f2   __attribute__((ext_vector_type(2)));
typedef float f16v __attribute__((ext_vector_type(16)));
typedef short s8v  __attribute__((ext_vector_type(8)));
typedef unsigned int u2v __attribute__((ext_vector_type(2)));
typedef unsigned int u4v __attribute__((ext_vector_type(4)));

#define SMEM_BYTES 24576   // union: attn 20.8K, proj 12K, outred 24K, prep 5K

struct Args {
  const float *xq, *xkv, *Wv, *Wo, *Wq, *Wk, *Uq, *Uk, *bq, *bk, *bv, *bo;
  const unsigned char* msk;
  unsigned short *xq_b, *xkv_b, *Wv_b, *Wo_b, *Atq, *Atk, *Qp, *Kp, *Vt, *P;
  float *bpq, *bpk, *denP, *Vsum, *out;
};

static __device__ __forceinline__ unsigned short f2b(float f) {
  __hip_bfloat16 h = __float2bfloat16(f);
  unsigned short u;
  __builtin_memcpy(&u, &h, 2);
  return u;
}
static __device__ __forceinline__ float b2f(unsigned short u) {
  __hip_bfloat16 h;
  __builtin_memcpy(&h, &u, 2);
  return __bfloat162float(h);
}
static __device__ __forceinline__ float fexp2(float x) {   // 2^x, 1 instr
  float r; asm("v_exp_f32 %0, %1" : "=v"(r) : "v"(x)); return r;
}

// async global->LDS, 16 B per lane. LDS dest wave-uniform base + lane*16.
static __device__ __forceinline__ void gld_lds16(const void* g, void* l) {
  __builtin_amdgcn_global_load_lds(
      (const __attribute__((address_space(1))) unsigned int*)g,
      (__attribute__((address_space(3))) unsigned int*)l, 16, 0, 0);
}

// ---------------------------------------------------------------------------
// STAGE 1: casts (all blocks, flat grid-stride over 2.62M float4) +
// fuse_w (id<512) + bias2 (id==512). Q-side scale = 0.25*log2(e).
// ---------------------------------------------------------------------------
#define QSCALE 0.36067376022224085f   // 0.25 * log2(e)

static __device__ void stage_prep(char* sm, int id, const Args& a) {
  const int tid = threadIdx.x;
  const int NF = TT*DM/4, NW = DM*DM/4;
  const int TOTC = 2*NF + 2*NW;
  for (int i = id*256 + tid; i < TOTC; i += 1024*256) {
    const float* s; unsigned short* d; int off;
    if (i < NF)           { s = a.xq;  d = a.xq_b;  off = i; }
    else if (i < 2*NF)    { s = a.xkv; d = a.xkv_b; off = i - NF; }
    else if (i < 2*NF+NW) { s = a.Wv;  d = a.Wv_b;  off = i - 2*NF; }
    else                  { s = a.Wo;  d = a.Wo_b;  off = i - 2*NF - NW; }
    const float4 v = ((const float4*)s)[off];
    ushort4 o;
    o.x = f2b(v.x); o.y = f2b(v.y); o.z = f2b(v.z); o.w = f2b(v.w);
    ((ushort4*)d)[off] = o;
  }
  if (id < 512) {
    // fuse_w job: sel = id>>8 (0=q, 1=k), f = id&255
    const int sel = id >> 8, f = id & 255;
    const float* W = sel ? a.Wk : a.Wq;
    const float* U = sel ? a.Uk : a.Uq;
    unsigned short* At = sel ? a.Atk : a.Atq;
    const float qs = sel ? 1.f : QSCALE;
    const int i0 = (f & 15) * 64, h = f >> 4;
    float* Us = (float*)sm;          // [64][16]
    float* Ws = (float*)sm + 1024;   // [4][64]
    const int il = tid & 63, rr = tid >> 6;
    for (int t = tid; t < 64*16; t += 256)
      Us[t] = U[(size_t)(h*DK + (t >> 4))*RK + (t & 15)];
    float acc[4] = {};
    for (int d0 = 0; d0 < DK; d0 += 4) {
      __syncthreads();
      Ws[rr*64 + il] = W[(size_t)(h*DK + d0 + rr)*DM + i0 + il];
      __syncthreads();
#pragma unroll
      for (int dd = 0; dd < 4; ++dd) {
        const float w = Ws[dd*64 + il];
#pragma unroll
        for (int j = 0; j < 4; ++j)
          acc[j] += w * Us[(d0 + dd)*16 + rr*4 + j];
      }
    }
#pragma unroll
    for (int j = 0; j < 4; ++j)
      At[(size_t)(h*RK + rr*4 + j)*DM + i0 + il] = f2b(acc[j] * qs);
  } else if (id == 512) {
    const int h = tid >> 4, r = tid & 15;
    float aq = 0.f, ak = 0.f;
    for (int d = 0; d < DK; ++d) {
      aq += a.bq[h*DK + d] * a.Uq[(size_t)(h*DK + d)*RK + r];
      ak += a.bk[h*DK + d] * a.Uk[(size_t)(h*DK + d)*RK + r];
    }
    a.bpq[tid] = aq * QSCALE;
    a.bpk[tid] = ak;
  }
}

// ---------------------------------------------------------------------------
// STAGE 2: id<256 QpKp 64x128 GEMM (packed store); id in [256,768) Vt
// 64x128 GEMM (transposed store). Single-buffered gld_lds staging.
// ---------------------------------------------------------------------------
static __device__ void stage_proj(char* sm, int id, const Args& a) {
  if (id >= 768) return;
  const int tid = threadIdx.x;
  const int wave = tid >> 6, lane = tid & 63;
  const int quad = lane >> 4, l15 = lane & 15;
  const int ar = tid >> 2, ac = (tid & 3) * 8;
  const f4 z = {0.f, 0.f, 0.f, 0.f};
  unsigned short* Xs = (unsigned short*)sm;          // 64x32  (4 KB)
  unsigned short* Bs = (unsigned short*)(sm + 4096); // 128x32 (8 KB)

  if (id < 256) {
    // ---- QpKp ----
    const int xb = id & 63, yb = (id >> 6) & 1, zb = id >> 7;
    const unsigned short* Ag = zb ? a.xkv_b : a.xq_b;
    const unsigned short* Bg = zb ? a.Atk : a.Atq;
    const float* bias = zb ? a.bpk : a.bpq;
    unsigned short* C = zb ? a.Kp : a.Qp;
    const int t0 = xb*64, n0 = yb*128, nh = wave*32;
    f4 acc[4][2];
#pragma unroll
    for (int q = 0; q < 4; ++q) { acc[q][0] = z; acc[q][1] = z; }
    for (int k0 = 0; k0 < DM; k0 += 32) {
      __syncthreads();
      gld_lds16(&Ag[(size_t)(t0 + ar)*DM + k0 + ac],      &Xs[wave*512]);
      gld_lds16(&Bg[(size_t)(n0 + ar)*DM + k0 + ac],      &Bs[wave*512]);
      gld_lds16(&Bg[(size_t)(n0 + 64 + ar)*DM + k0 + ac], &Bs[2048 + wave*512]);
      __syncthreads();
      s8v af[4], bf[2];
#pragma unroll
      for (int ms = 0; ms < 4; ++ms)
        af[ms] = *(const s8v*)&Xs[(ms*16 + l15)*32 + quad*8];
#pragma unroll
      for (int ns = 0; ns < 2; ++ns)
        bf[ns] = *(const s8v*)&Bs[(nh + ns*16 + l15)*32 + quad*8];
#pragma unroll
      for (int ms = 0; ms < 4; ++ms)
#pragma unroll
        for (int ns = 0; ns < 2; ++ns)
          acc[ms][ns] = __builtin_amdgcn_mfma_f32_16x16x32_bf16(
              af[ms], bf[ns], acc[ms][ns], 0, 0, 0);
    }
#pragma unroll
    for (int ms = 0; ms < 4; ++ms) {
      const int tb = t0 + ms*16 + quad*4;
#pragma unroll
      for (int ns = 0; ns < 2; ++ns) {
        const int o = n0 + nh + ns*16 + l15;
        const float bvv = bias[o];
        f4 v = acc[ms][ns];
#pragma unroll
        for (int rg = 0; rg < 4; ++rg) {
          const int tt = tb + rg;   // packed [b][h][l][16]
          C[(((size_t)(tt >> 11)*NH + (o >> 4))*LL + (tt & 2047))*RK + (o & 15)]
              = f2b(v[rg] + bvv);
        }
      }
    }
  } else {
    // ---- Vt: 64x128 tile, transposed store Vt[b][o][l] ----
    const int g = id - 256;
    const int t0 = (g & 63)*64, n0 = (g >> 6)*128, nh = wave*32;
    f4 acc[4][2];
#pragma unroll
    for (int q = 0; q < 4; ++q) { acc[q][0] = z; acc[q][1] = z; }
    for (int k0 = 0; k0 < DM; k0 += 32) {
      __syncthreads();
      gld_lds16(&a.xkv_b[(size_t)(t0 + ar)*DM + k0 + ac],     &Xs[wave*512]);
      gld_lds16(&a.Wv_b[(size_t)(n0 + ar)*DM + k0 + ac],      &Bs[wave*512]);
      gld_lds16(&a.Wv_b[(size_t)(n0 + 64 + ar)*DM + k0 + ac], &Bs[2048 + wave*512]);
      __syncthreads();
      s8v af[4], bf[2];
#pragma unroll
      for (int ms = 0; ms < 4; ++ms)
        af[ms] = *(const s8v*)&Xs[(ms*16 + l15)*32 + quad*8];
#pragma unroll
      for (int ns = 0; ns < 2; ++ns)
        bf[ns] = *(const s8v*)&Bs[(nh + ns*16 + l15)*32 + quad*8];
#pragma unroll
      for (int ms = 0; ms < 4; ++ms)
#pragma unroll
        for (int ns = 0; ns < 2; ++ns)
          acc[ms][ns] = __builtin_amdgcn_mfma_f32_16x16x32_bf16(
              af[ms], bf[ns], acc[ms][ns], 0, 0, 0);
    }
#pragma unroll
    for (int ms = 0; ms < 4; ++ms) {
      const int tb = t0 + ms*16 + quad*4;
#pragma unroll
      for (int ns = 0; ns < 2; ++ns) {
        const int o = n0 + nh + ns*16 + l15;
        const float bvv = a.bv[o];
        f4 v = acc[ms][ns];
        const int bb = tb >> 11, l = tb & 2047;
        ushort4 pk;
        pk.x = f2b(v[0] + bvv); pk.y = f2b(v[1] + bvv);
        pk.z = f2b(v[2] + bvv); pk.w = f2b(v[3] + bvv);
        *(ushort4*)&a.Vt[((size_t)bb*DM + o)*LL + l] = pk;
      }
    }
  }
}

// ---------------------------------------------------------------------------
// softmax + bf16-pack: scores pre-scaled by 0.25*log2e -> e^x == 2^s.
// E' = 2^s - 1 via v_pk_add_f32; den accumulated as pair-sums of E'.
// ---------------------------------------------------------------------------
template<bool MASKED>
static __device__ __forceinline__ void softmax_pack(
    const f16v& s0, const f16v& s1, const unsigned long long mb, const int hi,
    f2& den2, unsigned int (&Pd)[2][4][2]) {
  const f2 neg1 = {-1.f, -1.f};
#pragma unroll
  for (int nt = 0; nt < 2; ++nt) {
    const f16v& sv = nt ? s1 : s0;
#pragma unroll
    for (int r = 0; r < 4; ++r) {
#pragma unroll
      for (int jp = 0; jp < 2; ++jp) {
        f2 em2;
        em2[0] = fexp2(sv[r*4 + jp*2]);
        em2[1] = fexp2(sv[r*4 + jp*2 + 1]);
        if (MASKED) {
          const int kl = nt*32 + jp*2 + 8*r + 4*hi;
          if ((mb >> kl) & 1ull)       em2[0] = 0.f;
          if ((mb >> (kl + 1)) & 1ull) em2[1] = 0.f;
        }
        f2 ep2;
        asm("v_pk_add_f32 %0, %1, %2" : "=v"(ep2) : "v"(em2), "v"(neg1));
        asm("v_pk_add_f32 %0, %0, %1" : "+v"(den2) : "v"(ep2));
        asm("v_cvt_pk_bf16_f32 %0, %1, %2"
            : "=v"(Pd[nt][r][jp]) : "v"(ep2[0]), "v"(ep2[1]));
      }
    }
  }
}

// ---------------------------------------------------------------------------
// STAGE 3: attention (split-K, permlane32_swap PV assembly); id<32 also does
// the vsum job. denP stored [b][l][split][h] (transposed).
// ---------------------------------------------------------------------------
static __device__ void stage_attn(char* sm, int id, const Args& a) {
  const int tid = threadIdx.x;
  auto Ks = (unsigned short (*)[2][65][8])sm;            // [2][2][65][8]
  auto Vs = (unsigned short (*)[8][65][8])(sm + 4160);   // [2][8][65][8]

  const int q0 = (id & 15) * 128, h = (id >> 4) & 15;
  const int zz = id >> 8;
  const int b = zz & (BB - 1), ksp = zz >> 1;
  const int kbeg = ksp * (LL / NSPL);
  const int NT = (LL / NSPL) / 64;                       // 16 tiles
  const int w = tid >> 6, lane = tid & 63;
  const int l31 = lane & 31, hi = lane >> 5;

  const s8v qfrag = *(const s8v*)&a.Qp[
      (((size_t)b*NH + h)*LL + q0 + w*32 + l31)*RK + hi*8];

  const int sr = tid >> 2, sp = tid & 3;
  const unsigned short* __restrict__ Vrow =
      a.Vt + ((size_t)b*DM + h*DK + sr)*LL + kbeg;
  const unsigned short* __restrict__ Kbase =
      a.Kp + (((size_t)b*NH + h)*LL + kbeg + sr)*RK + sp*4;
  const unsigned char*  __restrict__ Mrow = a.msk + (size_t)b*LL + kbeg + lane;

  u2v kpre; s8v vpre0, vpre1;
  unsigned char mcur, mnext;

  kpre  = *(const u2v*)&Kbase[0];
  vpre0 = *(const s8v*)&Vrow[sp*16];
  vpre1 = *(const s8v*)&Vrow[sp*16 + 8];
  mcur  = Mrow[0];
  *(u2v*)&Ks[0][sp>>1][sr][(sp&1)*4] = kpre;
  *(s8v*)&Vs[0][sp*2][sr][0]   = vpre0;
  *(s8v*)&Vs[0][sp*2+1][sr][0] = vpre1;
  kpre  = *(const u2v*)&Kbase[(size_t)64*RK];
  vpre0 = *(const s8v*)&Vrow[64 + sp*16];
  vpre1 = *(const s8v*)&Vrow[64 + sp*16 + 8];
  mnext = Mrow[64];
  __syncthreads();

  f16v acc0, acc1, z16;
#pragma unroll
  for (int i = 0; i < 16; ++i) { acc0[i] = 0.f; acc1[i] = 0.f; z16[i] = 0.f; }
  f2 den2 = {0.f, 0.f};

  for (int t = 0; t < NT; ++t) {
    const int cur = t & 1;
    const unsigned long long mb = __ballot(mcur != 0);

    const s8v kf0 = *(const s8v*)&Ks[cur][hi][l31][0];
    const s8v kf1 = *(const s8v*)&Ks[cur][hi][32 + l31][0];

    const f16v s0 = __builtin_amdgcn_mfma_f32_32x32x16_bf16(kf0, qfrag, z16, 0, 0, 0);
    const f16v s1 = __builtin_amdgcn_mfma_f32_32x32x16_bf16(kf1, qfrag, z16, 0, 0, 0);

    unsigned int Pd[2][4][2];
    if (__builtin_expect(mb != 0ull, 0))
      softmax_pack<true >(s0, s1, mb, hi, den2, Pd);
    else
      softmax_pack<false>(s0, s1, mb, hi, den2, Pd);

#pragma unroll
    for (int kc = 0; kc < 4; ++kc) {
      const int nt = kc >> 1, aa = (kc & 1)*2;
      const u2v r0 = __builtin_amdgcn_permlane32_swap(
          Pd[nt][aa][0], Pd[nt][aa+1][0], false, false);
      const u2v r1 = __builtin_amdgcn_permlane32_swap(
          Pd[nt][aa][1], Pd[nt][aa+1][1], false, false);
      u4v efi;
      efi[0] = r0[0];
      efi[1] = r1[0];
      efi[2] = r0[1];
      efi[3] = r1[1];
      const s8v ef = __builtin_bit_cast(s8v, efi);
      const s8v vf0 = *(const s8v*)&Vs[cur][kc*2 + hi][l31][0];
      const s8v vf1 = *(const s8v*)&Vs[cur][kc*2 + hi][32 + l31][0];
      acc0 = __builtin_amdgcn_mfma_f32_32x32x16_bf16(ef, vf0, acc0, 0, 0, 0);
      acc1 = __builtin_amdgcn_mfma_f32_32x32x16_bf16(ef, vf1, acc1, 0, 0, 0);
    }

    if (t + 1 < NT) {
      *(u2v*)&Ks[cur^1][sp>>1][sr][(sp&1)*4] = kpre;
      *(s8v*)&Vs[cur^1][sp*2][sr][0]   = vpre0;
      *(s8v*)&Vs[cur^1][sp*2+1][sr][0] = vpre1;
      const int tn = (t + 2 < NT) ? t + 2 : NT - 1;
      kpre  = *(const u2v*)&Kbase[(size_t)tn*64*RK];
      vpre0 = *(const s8v*)&Vrow[tn*64 + sp*16];
      vpre1 = *(const s8v*)&Vrow[tn*64 + sp*16 + 8];
      mcur  = mnext;
      mnext = Mrow[tn*64];
    }
    __syncthreads();
  }

  // den = sum(E') + count; transposed store [b][l][split][h]
  float den = den2[0] + den2[1] + (float)(32 * NT);
  den += __shfl_xor(den, 32);
  if (hi == 0)
    a.denP[(((size_t)b*LL + q0 + w*32 + l31)*NSPL + ksp)*NH + h] = den;

#pragma unroll
  for (int rg = 0; rg < 16; ++rg) {
    const int qr = (rg & 3) + 8*(rg >> 2) + 4*hi;
    const size_t pbase =
        ((size_t)ksp*TT + b*LL + q0 + w*32 + qr)*DM + h*DK;
    a.P[pbase + l31]      = f2b(acc0[rg]);
    a.P[pbase + 32 + l31] = f2b(acc1[rg]);
  }

  // ---- vsum side-job on 32 blocks ----
  if (id < 32) {
    const int vh = id & 15, vb = id >> 4;
    const int d = tid >> 2, part = tid & 3;
    const unsigned short* row =
        a.Vt + ((size_t)vb*DM + vh*DK + d)*LL + part*512;
    float s = 0.f;
    for (int i = 0; i < 512; i += 8) {
      const s8v v = *(const s8v*)&row[i];
#pragma unroll
      for (int j = 0; j < 8; ++j) s += b2f((unsigned short)v[j]);
    }
    s += __shfl_xor(s, 1);
    s += __shfl_xor(s, 2);
    if (part == 0) a.Vsum[((size_t)vb*NH + vh)*DK + d] = s;
  }
}

// ---------------------------------------------------------------------------
// STAGE 4: out = ctx @ Wo^T + bo, ctx never materialized. Single-buffered;
// invS build coalesced from transposed denP. Index: global row (t0+r)
// already includes b*LL — do NOT add it again (r20 bug).
// ---------------------------------------------------------------------------
static __device__ void stage_outred(char* sm, int id, const Args& a) {
  if (id >= 512) return;
  const int tid = threadIdx.x;
  unsigned short* P0s = (unsigned short*)sm;            // [2048]  4 KB
  unsigned short* P1s = (unsigned short*)(sm + 4096);   // [2048]  4 KB
  unsigned short* Bss = (unsigned short*)(sm + 8192);   // [4096]  8 KB
  float* vsS  = (float*)(sm + 16384);                   // [1024]  4 KB
  float* invS = (float*)(sm + 20480);                   // [64*16] 4 KB

  const int t0 = (id & 63) * 64, n0 = (id >> 6) * 128;
  const int wave = tid >> 6, lane = tid & 63;
  const int quad = lane >> 4, l15 = lane & 15;
  const int nh = wave * 32;
  const int ar = tid >> 2, ac = (tid & 3) * 8;
  const int trow = t0 + ar;
  const int b = t0 >> 11;

  for (int i = tid; i < 1024; i += 256)
    vsS[i] = a.Vsum[(size_t)b*DM + i];
  {
    const int r = tid >> 2, h0 = (tid & 3) * 4;
    // global row (t0+r) == b*LL + l  -> stride NSPL*NH (FIXED: no extra b*LL)
    const size_t base = (size_t)(t0 + r) * (NSPL*NH);
    const f4 d0 = *(const f4*)&a.denP[base + h0];        // split 0
    const f4 d1 = *(const f4*)&a.denP[base + NH + h0];   // split 1
#pragma unroll
    for (int j = 0; j < 4; ++j)
      invS[r*16 + h0 + j] = 1.f / fmaxf(d0[j] + d1[j], 1e-30f);
  }

  const f4 z = {0.f, 0.f, 0.f, 0.f};
  f4 acc[4][2];
#pragma unroll
  for (int q = 0; q < 4; ++q) { acc[q][0] = z; acc[q][1] = z; }

  for (int k0 = 0; k0 < DM; k0 += 32) {
    __syncthreads();
    gld_lds16(&a.P[(size_t)trow*DM + k0 + ac],              &P0s[wave*512]);
    gld_lds16(&a.P[((size_t)TT + trow)*DM + k0 + ac],       &P1s[wave*512]);
    gld_lds16(&a.Wo_b[(size_t)(n0 + ar)*DM + k0 + ac],      &Bss[wave*512]);
    gld_lds16(&a.Wo_b[(size_t)(n0 + 64 + ar)*DM + k0 + ac], &Bss[2048 + wave*512]);
    __syncthreads();

    const int hk = k0 >> 6;
    const f4 vq0 = *(const f4*)&vsS[k0 + quad*8];
    const f4 vq1 = *(const f4*)&vsS[k0 + quad*8 + 4];
    s8v af[4], bf[2];
#pragma unroll
    for (int ms = 0; ms < 4; ++ms) {
      const int r16 = ms*16 + l15;
      const float inv = invS[r16*16 + hk];
      const s8v p0 = *(const s8v*)&P0s[r16*32 + quad*8];
      const s8v p1 = *(const s8v*)&P1s[r16*32 + quad*8];
      float e[8];
#pragma unroll
      for (int j = 0; j < 4; ++j) {
        e[j]     = (vq0[j] + b2f((unsigned short)p0[j])
                           + b2f((unsigned short)p1[j])) * inv;
        e[4 + j] = (vq1[j] + b2f((unsigned short)p0[4+j])
                           + b2f((unsigned short)p1[4+j])) * inv;
      }
      unsigned int d0, d1, d2, d3;
      asm("v_cvt_pk_bf16_f32 %0, %1, %2" : "=v"(d0) : "v"(e[0]), "v"(e[1]));
      asm("v_cvt_pk_bf16_f32 %0, %1, %2" : "=v"(d1) : "v"(e[2]), "v"(e[3]));
      asm("v_cvt_pk_bf16_f32 %0, %1, %2" : "=v"(d2) : "v"(e[4]), "v"(e[5]));
      asm("v_cvt_pk_bf16_f32 %0, %1, %2" : "=v"(d3) : "v"(e[6]), "v"(e[7]));
      u4v efi; efi[0] = d0; efi[1] = d1; efi[2] = d2; efi[3] = d3;
      af[ms] = __builtin_bit_cast(s8v, efi);
    }
#pragma unroll
    for (int ns = 0; ns < 2; ++ns)
      bf[ns] = *(const s8v*)&Bss[(nh + ns*16 + l15)*32 + quad*8];
#pragma unroll
    for (int ms = 0; ms < 4; ++ms)
#pragma unroll
      for (int ns = 0; ns < 2; ++ns)
        acc[ms][ns] = __builtin_amdgcn_mfma_f32_16x16x32_bf16(
            af[ms], bf[ns], acc[ms][ns], 0, 0, 0);
  }

#pragma unroll
  for (int ms = 0; ms < 4; ++ms) {
    const int tb = t0 + ms*16 + quad*4;
#pragma unroll
    for (int ns = 0; ns < 2; ++ns) {
      const int o = n0 + nh + ns*16 + l15;
      const float bvv = a.bo[o];
      f4 v = acc[ms][ns];
#pragma unroll
      for (int rg = 0; rg < 4; ++rg)
        a.out[(size_t)(tb + rg)*DM + o] = v[rg] + bvv;
    }
  }
}

// ---------------------------------------------------------------------------
// Fused cooperative kernel + classic fallback wrappers (same stage code).
// ---------------------------------------------------------------------------
__global__ __launch_bounds__(256, 4) void fused_all(Args a) {
  __shared__ __align__(16) char sm[SMEM_BYTES];
  cg::grid_group grid = cg::this_grid();
  const int id = blockIdx.x;
  stage_prep(sm, id, a);
  grid.sync();
  stage_proj(sm, id, a);
  grid.sync();
  stage_attn(sm, id, a);
  grid.sync();
  stage_outred(sm, id, a);
}

__global__ __launch_bounds__(256, 4) void prep_w(Args a) {
  __shared__ __align__(16) char sm[SMEM_BYTES];
  stage_prep(sm, blockIdx.x, a);
}
__global__ __launch_bounds__(256, 4) void proj_w(Args a) {
  __shared__ __align__(16) char sm[SMEM_BYTES];
  stage_proj(sm, blockIdx.x, a);
}
__global__ __launch_bounds__(256, 4) void attn_w(Args a) {
  __shared__ __align__(16) char sm[SMEM_BYTES];
  stage_attn(sm, blockIdx.x, a);
}
__global__ __launch_bounds__(256, 4) void outred_w(Args a) {
  __shared__ __align__(16) char sm[SMEM_BYTES];
  stage_outred(sm, blockIdx.x, a);
}

// ---------------------------------------------------------------------------
extern "C" void kernel_launch(void* const* d_in, const int* in_sizes, int n_in,
                              void* d_out, int out_size, void* d_ws, size_t ws_size,
                              hipStream_t stream) {
  (void)in_sizes; (void)n_in; (void)out_size; (void)ws_size;
  // Workspace layout, ~33.6 MiB. P ([2][TT][DM] bf16, 16 MB) aliases
  // xq_b+xkv_b (dead after proj).
  char* w = (char*)d_ws;
  Args a;
  a.xq    = (const float*)d_in[0];
  a.xkv   = (const float*)d_in[1];
  a.Wq    = (const float*)d_in[2];
  a.bq    = (const float*)d_in[3];
  a.Wk    = (const float*)d_in[4];
  a.bk    = (const float*)d_in[5];
  a.Wv    = (const float*)d_in[6];
  a.bv    = (const float*)d_in[7];
  a.Wo    = (const float*)d_in[8];
  a.bo    = (const float*)d_in[9];
  a.Uq    = (const float*)d_in[10];
  a.Uk    = (const float*)d_in[11];
  a.msk   = (const unsigned char*)d_in[12];
  a.xq_b  = (unsigned short*)(w);             //  8 MB
  a.xkv_b = (unsigned short*)(w +  8388608);  //  8 MB
  a.Wv_b  = (unsigned short*)(w + 16777216);  //  2 MB
  a.Wo_b  = (unsigned short*)(w + 18874368);  //  2 MB
  a.Atq   = (unsigned short*)(w + 20971520);  //  0.5 MB
  a.Atk   = (unsigned short*)(w + 21495808);  //  0.5 MB
  a.bpq   = (float*)(w + 22020096);           //  1 KB
  a.bpk   = (float*)(w + 22021120);           //  1 KB
  a.Qp    = (unsigned short*)(w + 22022144);  //  2 MB
  a.Kp    = (unsigned short*)(w + 24119296);  //  2 MB
  a.Vt    = (unsigned short*)(w + 26216448);  //  8 MB
  a.Vsum  = (float*)(w + 34605056);           //  8 KB
  a.denP  = (float*)(w + 34613248);           //  512 KB  [b][l][s][h]
  a.P     = (unsigned short*)w;               //  16 MB aliased
  a.out   = (float*)d_out;

  int dev = 0, coop = 0, ncu = 0, nblk = 0;
  hipGetDevice(&dev);
  hipDeviceGetAttribute(&coop, hipDeviceAttributeCooperativeLaunch, dev);
  hipDeviceGetAttribute(&ncu, hipDeviceAttributeMultiprocessorCount, dev);
  hipOccupancyMaxActiveBlocksPerMultiprocessor(
      &nblk, (const void*)fused_all, 256, 0);

  if (coop && (long)nblk * ncu >= 1024) {
    void* kargs[] = {(void*)&a};
    hipLaunchCooperativeKernel((const void*)fused_all,
                               dim3(1024), dim3(256), kargs, 0, stream);
  } else {
    prep_w<<<1024, 256, 0, stream>>>(a);
    proj_w<<<768, 256, 0, stream>>>(a);
    attn_w<<<1024, 256, 0, stream>>>(a);
    outred_w<<<512, 256, 0, stream>>>(a);
  }
}